// Round 2
// baseline (212.325 us; speedup 1.0000x reference)
//
#include <hip/hip_runtime.h>

#define NT 8
#define NY 32
#define NX 32
#define NN 1024  // NY*NX

// Stencil coefficients of M = I + A for one node. c[(ry+1)*3+(rx+1)] is the
// coefficient toward target offset (ry,rx); zeroed when the TARGET node falls
// off-grid (matches reference `valid` masking on the column node).
__device__ __forceinline__ void node_coefs(const float* __restrict__ kap,
                                           const float* __restrict__ m,
                                           const float* __restrict__ H,
                                           const float* __restrict__ tau,
                                           int b, int node, int tc,
                                           int iy, int ix,
                                           float* c /*[9]*/, float& w) {
    const int base = node * NT + tc;                 // [.., node, t] layout, last dim NT
    const float kp  = kap[(b * NN) * NT + base];
    const float m1  = m[((b * 2 + 0) * NN) * NT + base];
    const float m2  = m[((b * 2 + 1) * NN) * NT + base];
    const float h11 = H[((b * 4 + 0) * NN) * NT + base];
    const float h12 = H[((b * 4 + 1) * NN) * NT + base];
    const float h22 = H[((b * 4 + 3) * NN) * NT + base];
    const float tv  = tau[(b * NN) * NT + base];
    w = 1.0f / (tv * tv);

    const float cxy = 0.5f * h12;
    const bool ym = iy > 0, yp = iy < NY - 1;
    const bool xm = ix > 0, xp = ix < NX - 1;

    c[4] = 1.0f + kp * kp + 2.0f * h11 + 2.0f * h22;
    c[0] = (ym && xm) ? -cxy               : 0.0f;
    c[1] =  ym        ? (-h22 - 0.5f * m2) : 0.0f;
    c[2] = (ym && xp) ?  cxy               : 0.0f;
    c[3] =  xm        ? (-h11 - 0.5f * m1) : 0.0f;
    c[5] =  xp        ? (-h11 + 0.5f * m1) : 0.0f;
    c[6] = (yp && xm) ?  cxy               : 0.0f;
    c[7] =  yp        ? (-h22 + 0.5f * m2) : 0.0f;
    c[8] = (yp && xp) ? -cxy               : 0.0f;
}

// One block per (b, t); thread j = node. Emits:
//   U[(b,t,node,q)]  = -w * c[q]                         (9 floats/node)
//   D0[(b,t,row,v)]  = 5x5 window of M^T diag(w) M (+w_next on center) (25/row)
__global__ __launch_bounds__(1024) void precompute_kernel(
        const float* __restrict__ kap, const float* __restrict__ m,
        const float* __restrict__ H, const float* __restrict__ tau,
        float* __restrict__ U, float* __restrict__ D0) {
    __shared__ float sc[NN][9];
    __shared__ float sw[NN];

    const int bt = blockIdx.x;         // b*NT + t
    const int b = bt >> 3, t = bt & 7;
    const int j = threadIdx.x;
    const int jy = j >> 5, jx = j & 31;

    float c[9], w;
    node_coefs(kap, m, H, tau, b, j, t, jy, jx, c, w);

    {   // U: own-node values, no neighbors needed
        float* up = U + ((size_t)bt * NN + j) * 9;
        #pragma unroll
        for (int q = 0; q < 9; ++q) up[q] = -w * c[q];
    }
    #pragma unroll
    for (int q = 0; q < 9; ++q) sc[j][q] = c[q];
    sw[j] = w;
    __syncthreads();

    // w_{t+1}[j] for the diagonal term
    float wnext = 0.0f;
    if (t < NT - 1) {
        const float tv = tau[((size_t)b * NN + j) * NT + (t + 1)];
        wnext = 1.0f / (tv * tv);
    }

    float* dp = D0 + ((size_t)bt * NN + j) * 25;
    #pragma unroll
    for (int dy = -2; dy <= 2; ++dy) {
        #pragma unroll
        for (int dx = -2; dx <= 2; ++dx) {
            float acc = 0.0f;
            #pragma unroll
            for (int d = 0; d < 9; ++d) {   // neighbor rows i = j + (ey,ex)
                const int ey = d / 3 - 1, ex = d % 3 - 1;
                const int r2y = dy - ey, r2x = dx - ex;
                if (r2y < -1 || r2y > 1 || r2x < -1 || r2x > 1) continue;
                const int iy = jy + ey, ix = jx + ex;
                if (iy < 0 || iy >= NY || ix < 0 || ix >= NX) continue;
                const int jn = iy * NX + ix;
                acc += sw[jn] * sc[jn][8 - d] * sc[jn][(r2y + 1) * 3 + (r2x + 1)];
            }
            if (dy == 0 && dx == 0) acc += wnext;
            dp[(dy + 2) * 5 + (dx + 2)] = acc;
        }
    }
}

// Pure streaming writer: one thread per float4 of output. No LDS, no syncs.
__global__ __launch_bounds__(256) void writer_kernel(
        const float* __restrict__ U, const float* __restrict__ D0,
        float* __restrict__ out) {
    const unsigned gid = blockIdx.x * 256u + threadIdx.x;   // quad index
    const unsigned row = gid >> 8;
    const unsigned q   = gid & 255u;

    const int j   = row & (NN - 1);
    const int t   = (row >> 10) & 7;
    const int bb  = row >> 13;          // b*3 + blk
    const int blk = bb % 3;
    const int b   = bb / 3;
    const int jy = j >> 5, jx = j & 31;
    const int cy = q >> 3;              // column y (quad spans 4 cols, same cy)
    const int cx0 = (q & 7) * 4;

    float4 v = make_float4(0.f, 0.f, 0.f, 0.f);
    float* vp = &v.x;
    const int ddy = cy - jy;

    if (blk == 0) {
        if (ddy >= -2 && ddy <= 2) {
            const float* base = D0 + ((size_t)(b * NT + t) * NN + j) * 25
                                   + (ddy + 2) * 5;
            #pragma unroll
            for (int qq = 0; qq < 4; ++qq) {
                const int ddx = cx0 + qq - jx;
                if (ddx >= -2 && ddx <= 2) vp[qq] = base[ddx + 2];
            }
        }
    } else if (blk == 1) {
        if (t > 0 && ddy >= -1 && ddy <= 1) {
            // lower[t][j][k] = -w_t[k] M_t[k,j] = U[(b,t,k)][8-off]
            #pragma unroll
            for (int qq = 0; qq < 4; ++qq) {
                const int ddx = cx0 + qq - jx;
                if (ddx >= -1 && ddx <= 1) {
                    const int k = (cy * NX) + (cx0 + qq);
                    const int off = (ddy + 1) * 3 + (ddx + 1);
                    vp[qq] = U[((size_t)(b * NT + t) * NN + k) * 9 + (8 - off)];
                }
            }
        }
    } else {
        if (t < NT - 1 && ddy >= -1 && ddy <= 1) {
            // upper[t][j][k] = -w_{t+1}[j] M_{t+1}[j,k] = U[(b,t+1,j)][off]
            const float* up = U + ((size_t)(b * NT + t + 1) * NN + j) * 9
                                + (ddy + 1) * 3;
            #pragma unroll
            for (int qq = 0; qq < 4; ++qq) {
                const int ddx = cx0 + qq - jx;
                if (ddx >= -1 && ddx <= 1) vp[qq] = up[ddx + 1];
            }
        }
    }

    float4* op = (float4*)out;
    op[gid] = v;
}

extern "C" void kernel_launch(void* const* d_in, const int* in_sizes, int n_in,
                              void* d_out, int out_size, void* d_ws, size_t ws_size,
                              hipStream_t stream) {
    const float* kap = (const float*)d_in[0];  // [n_b,1,N,NT]
    const float* m   = (const float*)d_in[1];  // [n_b,2,N,NT]
    const float* H   = (const float*)d_in[2];  // [n_b,2,2,N,NT]
    const float* tau = (const float*)d_in[3];  // [n_b,1,N,NT]
    float* out = (float*)d_out;                // [n_b,3,NT,N,N]

    const int n_b = in_sizes[0] / (NN * NT);

    float* U  = (float*)d_ws;                              // n_b*NT*NN*9
    float* D0 = U + (size_t)n_b * NT * NN * 9;             // n_b*NT*NN*25

    precompute_kernel<<<n_b * NT, 1024, 0, stream>>>(kap, m, H, tau, U, D0);

    const unsigned total_quads = (unsigned)n_b * 3u * NT * NN * (NN / 4);
    writer_kernel<<<total_quads / 256u, 256, 0, stream>>>(U, D0, out);
}